// Round 5
// baseline (1140.249 us; speedup 1.0000x reference)
//
#include <hip/hip_runtime.h>

typedef unsigned short u16;
typedef unsigned int   u32;

#define DEVINL __device__ __forceinline__

// ---- problem constants (f32 problem: all float inputs/outputs are f32) --
#define NLOC 1024
#define NNEI 64
#define NDIM 128
#define EDIM 64
#define ADIM 64
#define ASEL 20

// ---- static device workspace -------------------------------------------
enum : size_t {
  WS_NSELF = 0,                        // [1024,128] silu(node@W_self+b)
  WS_NW0   = WS_NSELF + 1024*128,      // [1024,128] node@W0 + b_ne
  WS_NV0   = WS_NW0   + 1024*128,      // [1024,64]  node@V0 + b_es
  WS_NA1   = WS_NV0   + 1024*64,       // [1024,64]  node@A1 + b_ea1
  WS_NB1   = WS_NA1   + 1024*64,       // [1024,64]  node@B1 + b_as
  WS_A0T   = WS_NB1   + 1024*64,       // [64,64] A0^T
  WS_B0T   = WS_A0T   + 64*64,         // [64,64] B0^T
  WS_F32_END = WS_B0T + 64*64
};
__device__ float g_ws[WS_F32_END];
__device__ float g_red[1024*ASEL*64];   // reduced (K2 -> K3)

DEVINL float siluf(float x) {
  return x * __builtin_amdgcn_rcpf(1.0f + __expf(-x));
}

// =========================================================================
// K0: per-node projections. grid=1024 x 128.
// =========================================================================
__global__ __launch_bounds__(128) void k0_node_pre(
    const float* __restrict__ node,
    const float* __restrict__ W_self, const float* __restrict__ b_self,
    const float* __restrict__ W_ne,   const float* __restrict__ b_ne,
    const float* __restrict__ W_es,   const float* __restrict__ b_es,
    const float* __restrict__ W_ea1,  const float* __restrict__ b_ea1,
    const float* __restrict__ W_as,   const float* __restrict__ b_as)
{
  const int l = blockIdx.x, t = threadIdx.x;
  __shared__ float nl[128];
  nl[t] = node[l*128 + t];
  __syncthreads();
  float aS = b_self[t];
  float aW = b_ne[t];
  #pragma unroll 8
  for (int k = 0; k < 128; ++k) {
    float nv = nl[k];
    aS = fmaf(nv, W_self[k*128 + t], aS);
    aW = fmaf(nv, W_ne[k*128 + t], aW);
  }
  g_ws[WS_NSELF + l*128 + t] = siluf(aS);
  g_ws[WS_NW0   + l*128 + t] = aW;
  if (t < 64) {
    float aV = b_es[t], aA = b_ea1[t], aB = b_as[t];
    #pragma unroll 8
    for (int k = 0; k < 128; ++k) {
      float nv = nl[k];
      aV = fmaf(nv, W_es[k*64 + t], aV);
      aA = fmaf(nv, W_ea1[(64 + k)*64 + t], aA);
      aB = fmaf(nv, W_as[(64 + k)*64 + t], aB);
    }
    g_ws[WS_NV0 + l*64 + t] = aV;
    g_ws[WS_NA1 + l*64 + t] = aA;
    g_ws[WS_NB1 + l*64 + t] = aB;
  }
}

// =========================================================================
// Kw: transpose A0 (W_ea1 rows 0..63) / B0 (W_as rows 0..63).
// A0T[d*64+k] = A0[k][d]  -> contiguous wave-uniform scalar loads in K2.
// =========================================================================
__global__ __launch_bounds__(256) void kw_prep(
    const float* __restrict__ W_ea1, const float* __restrict__ W_as)
{
  int e = blockIdx.x*256 + threadIdx.x;   // 0..8191
  if (e < 4096) {
    int d = e >> 6, k = e & 63;
    g_ws[WS_A0T + e] = W_ea1[k*64 + d];
  } else {
    int e2 = e - 4096;
    int d = e2 >> 6, k = e2 & 63;
    g_ws[WS_B0T + e2] = W_as[k*64 + d];
  }
}

// =========================================================================
// K2: angle kernel. grid=1024 x 256.
//   Stage 1: e_ang @ {A2,A3,B2,B3} into LDS (weights staged in LDS).
//   Stage 2: lane owns pair p=(i,j); d-loop; A0T/B0T columns via s_loads.
//            pre_A -> silu -> LDS-atomic j-reduction -> g_red
//            pre_B -> silu -> angle_out
// =========================================================================
__global__ __launch_bounds__(256) void k2_angle(
    const float* __restrict__ ang,
    const float* __restrict__ edge,
    const float* __restrict__ a_sw,
    const float* __restrict__ res_a,
    const float* __restrict__ W_ea1, const float* __restrict__ W_as,
    float* __restrict__ angle_out)
{
  const int l = blockIdx.x, t = threadIdx.x;
  __shared__ float Wl[64*64];
  __shared__ float eang[ASEL*65];
  __shared__ float eA2l[ASEL*65], eA3l[ASEL*65], eB2l[ASEL*65], eB3l[ASEL*65];
  __shared__ float red[ASEL*65];
  __shared__ float aswl[32], nA1l[64], nB1l[64], resal[64];

  for (int e = t; e < ASEL*65; e += 256) red[e] = 0.f;
  for (int e = t; e < ASEL*64; e += 256)
    eang[(e >> 6)*65 + (e & 63)] = edge[l*4096 + e];
  if (t < ASEL) aswl[t] = a_sw[l*ASEL + t];
  if (t < 64) {
    nA1l[t]  = g_ws[WS_NA1 + l*64 + t];
    nB1l[t]  = g_ws[WS_NB1 + l*64 + t];
    resal[t] = res_a[t];
  }

  // e_ang projections: A2 / A3 / B2 / B3 (no LDS-pointer arrays on gfx950)
  const int o = t & 63, wv = t >> 6;
  #pragma unroll 1
  for (int m = 0; m < 4; ++m) {
    __syncthreads();
    const float* Wm = (m == 0) ? (W_ea1 + 192*64)
                    : (m == 1) ? (W_ea1 + 256*64)
                    : (m == 2) ? (W_as  + 192*64)
                    :            (W_as  + 256*64);
    for (int e = t; e < 4096; e += 256) Wl[e] = Wm[e];
    __syncthreads();
    float* outm = (m == 0) ? eA2l : (m == 1) ? eA3l : (m == 2) ? eB2l : eB3l;
    for (int j = wv; j < ASEL; j += 4) {
      float acc = 0.f;
      #pragma unroll 8
      for (int k = 0; k < 64; ++k)
        acc = fmaf(eang[j*65 + k], Wl[k*64 + o], acc);
      outm[j*65 + o] = acc;
    }
  }
  __syncthreads();

  const float* __restrict__ A0T = g_ws + WS_A0T;
  const float* __restrict__ B0T = g_ws + WS_B0T;

  #pragma unroll 1
  for (int rep = 0; rep < 2; ++rep) {
    int p = rep*256 + t;
    if (p < 400) {
      int i = p / 20, j = p % 20;
      size_t rowoff = (size_t)(l*400 + p)*64;
      float a[64];
      {
        const float4* a4 = reinterpret_cast<const float4*>(ang + rowoff);
        #pragma unroll
        for (int q = 0; q < 16; ++q) {
          float4 u = a4[q];
          a[q*4+0] = u.x; a[q*4+1] = u.y; a[q*4+2] = u.z; a[q*4+3] = u.w;
        }
      }
      float aswj = aswl[j];
      #pragma unroll 1
      for (int d = 0; d < 64; ++d) {
        float baseA = nA1l[d] + eA2l[j*65 + d] + eA3l[i*65 + d];
        float baseB = nB1l[d] + eB2l[j*65 + d] + eB3l[i*65 + d];
        const float* __restrict__ ca = A0T + d*64;   // wave-uniform -> s_load
        const float* __restrict__ cb = B0T + d*64;
        float aA0 = 0.f, aA1 = 0.f, aB0 = 0.f, aB1 = 0.f;
        #pragma unroll
        for (int k = 0; k < 64; k += 2) {
          aA0 = fmaf(a[k],   ca[k],   aA0);
          aB0 = fmaf(a[k],   cb[k],   aB0);
          aA1 = fmaf(a[k+1], ca[k+1], aA1);
          aB1 = fmaf(a[k+1], cb[k+1], aB1);
        }
        float preA = baseA + aA0 + aA1;
        float preB = baseB + aB0 + aB1;
        atomicAdd(&red[i*65 + d], aswj * siluf(preA));
        float orig = ang[rowoff + d];   // reload (avoids dynamic reg index)
        angle_out[rowoff + d] = orig + resal[d]*siluf(preB);
      }
    }
  }
  __syncthreads();
  const float rs = 0.22360679775f;   // 1/sqrt(20)
  for (int e = t; e < ASEL*64; e += 256) {
    int i = e >> 6, d = e & 63;
    g_red[(l*ASEL + i)*64 + d] = aswl[i] * red[i*65 + d] * rs;
  }
}

// =========================================================================
// K3: node + edge kernel. grid=1024 x 256.
// =========================================================================
__global__ __launch_bounds__(256) void k3_node_edge(
    const float* __restrict__ node_ext,
    const float* __restrict__ edge,
    const float* __restrict__ h2,
    const float* __restrict__ sw,
    const int* __restrict__ nlist,
    const float* __restrict__ W_sym, const float* __restrict__ b_sym,
    const float* __restrict__ W_ne,  const float* __restrict__ W_es,
    const float* __restrict__ W_ea2, const float* __restrict__ b_ea2,
    const float* __restrict__ res_n, const float* __restrict__ res_e,
    float* __restrict__ node_out,
    float* __restrict__ edge_out)
{
  const int l = blockIdx.x, t = threadIdx.x;
  __shared__ float Ef[64*64];
  __shared__ float Nf[64*128];
  __shared__ float hwv[64*4];
  __shared__ float swl[64];
  __shared__ float hgE[3*64], hgN[3*128];
  __shared__ float cat[768];
  __shared__ float nsym[128];
  __shared__ float msgl[ASEL*64];
  __shared__ float msgc[64];

  for (int e = t; e < 4096; e += 256) Ef[e] = edge[l*4096 + e];
  for (int e = t; e < 8192; e += 256) {
    int n = e >> 7, k = e & 127;
    int idx = nlist[l*64 + n];
    Nf[e] = node_ext[(size_t)idx*128 + k];
  }
  if (t < 64) {
    float s = sw[l*64 + t];
    swl[t] = s;
    hwv[t*4+0] = h2[(l*64 + t)*3 + 0] * s;
    hwv[t*4+1] = h2[(l*64 + t)*3 + 1] * s;
    hwv[t*4+2] = h2[(l*64 + t)*3 + 2] * s;
  }
  __syncthreads();

  // hg = (h2*sw)^T @ G / 64
  for (int e = t; e < 192; e += 256) {
    int tt = e >> 6, d = e & 63;
    float acc = 0.f;
    #pragma unroll 4
    for (int n = 0; n < 64; ++n) acc = fmaf(hwv[n*4 + tt], Ef[n*64 + d], acc);
    hgE[tt*64 + d] = acc * (1.f/64.f);
  }
  for (int e = t; e < 384; e += 256) {
    int tt = e >> 7, k = e & 127;
    float acc = 0.f;
    #pragma unroll 4
    for (int n = 0; n < 64; ++n) acc = fmaf(hwv[n*4 + tt], Nf[n*128 + k], acc);
    hgN[tt*128 + k] = acc * (1.f/64.f);
  }
  __syncthreads();

  // cat = [grrg(edge)(4x64), grrg(nei)(4x128)]
  for (int e = t; e < 256; e += 256) {
    int a = e >> 6, d = e & 63;
    cat[e] = (hgE[a]*hgE[d] + hgE[64 + a]*hgE[64 + d] + hgE[128 + a]*hgE[128 + d]) * (1.f/3.f);
  }
  for (int e = t; e < 512; e += 256) {
    int a = e >> 7, k = e & 127;
    cat[256 + e] = (hgN[a]*hgN[k] + hgN[128 + a]*hgN[128 + k] + hgN[256 + a]*hgN[256 + k]) * (1.f/3.f);
  }
  __syncthreads();

  // node_sym (threads 0-127) and e_angle_msg (threads 128-255)
  if (t < 128) {
    float acc = b_sym[t];
    #pragma unroll 4
    for (int c = 0; c < 768; ++c)
      acc = fmaf(cat[c], W_sym[c*128 + t], acc);
    nsym[t] = siluf(acc);
  } else {
    int idx = t - 128;
    if (idx < 64) msgc[idx] = siluf(b_ea2[idx]);
    for (int q = 0; q < 10; ++q) {
      int e = q*128 + idx;
      int n = e >> 6, oo = e & 63;
      float acc = b_ea2[oo];
      #pragma unroll 4
      for (int k = 0; k < 64; ++k)
        acc = fmaf(g_red[(l*ASEL + n)*64 + k], W_ea2[k*64 + oo], acc);
      msgl[e] = siluf(acc);
    }
  }
  __syncthreads();

  // main GEMM: 64 nei-rows x (128 ne-cols + 64 es-cols)
  if (t < 128) {
    const int c = t;
    float colbase = g_ws[WS_NW0 + l*128 + c];
    float nedge = 0.f;
    for (int nt4 = 0; nt4 < 4; ++nt4) {
      float acc[16];
      #pragma unroll
      for (int nn = 0; nn < 16; ++nn) acc[nn] = colbase;
      #pragma unroll 4
      for (int k = 0; k < 128; ++k) {
        float w = W_ne[(128 + k)*128 + c];
        #pragma unroll
        for (int nn = 0; nn < 16; ++nn)
          acc[nn] = fmaf(Nf[(nt4*16 + nn)*128 + k], w, acc[nn]);
      }
      #pragma unroll 4
      for (int k = 0; k < 64; ++k) {
        float w = W_ne[(256 + k)*128 + c];
        #pragma unroll
        for (int nn = 0; nn < 16; ++nn)
          acc[nn] = fmaf(Ef[(nt4*16 + nn)*64 + k], w, acc[nn]);
      }
      #pragma unroll
      for (int nn = 0; nn < 16; ++nn)
        nedge = fmaf(siluf(acc[nn]), swl[nt4*16 + nn], nedge);
    }
    nedge *= (1.f/64.f);
    float nodev = node_ext[l*128 + c];
    float outv = nodev + res_n[c]*g_ws[WS_NSELF + l*128 + c]
               + res_n[128 + c]*nsym[c] + res_n[256 + c]*nedge;
    node_out[l*128 + c] = outv;
  } else if (t < 192) {
    const int o = t - 128;
    float colbase = g_ws[WS_NV0 + l*64 + o];
    float re0 = res_e[o], re1 = res_e[64 + o];
    float msgcv = msgc[o];
    for (int nt4 = 0; nt4 < 4; ++nt4) {
      float acc[16];
      #pragma unroll
      for (int nn = 0; nn < 16; ++nn) acc[nn] = colbase;
      #pragma unroll 4
      for (int k = 0; k < 128; ++k) {
        float w = W_es[(128 + k)*64 + o];
        #pragma unroll
        for (int nn = 0; nn < 16; ++nn)
          acc[nn] = fmaf(Nf[(nt4*16 + nn)*128 + k], w, acc[nn]);
      }
      #pragma unroll 4
      for (int k = 0; k < 64; ++k) {
        float w = W_es[(256 + k)*64 + o];
        #pragma unroll
        for (int nn = 0; nn < 16; ++nn)
          acc[nn] = fmaf(Ef[(nt4*16 + nn)*64 + k], w, acc[nn]);
      }
      #pragma unroll
      for (int nn = 0; nn < 16; ++nn) {
        int n = nt4*16 + nn;
        float s = siluf(acc[nn]);
        float msgv = (n < ASEL) ? msgl[n*64 + o] : msgcv;
        edge_out[(size_t)l*4096 + n*64 + o] = Ef[n*64 + o] + re0*s + re1*msgv;
      }
    }
  }
}

// =========================================================================
extern "C" void kernel_launch(void* const* d_in, const int* in_sizes, int n_in,
                              void* d_out, int out_size, void* d_ws, size_t ws_size,
                              hipStream_t stream) {
  const float* node_ext = (const float*)d_in[0];
  const float* edge_ebd = (const float*)d_in[1];
  const float* h2       = (const float*)d_in[2];
  const float* angle    = (const float*)d_in[3];
  const float* sw       = (const float*)d_in[4];
  const float* a_sw     = (const float*)d_in[5];
  const float* W_self   = (const float*)d_in[6];
  const float* b_self   = (const float*)d_in[7];
  const float* W_sym    = (const float*)d_in[8];
  const float* b_sym    = (const float*)d_in[9];
  const float* W_ne     = (const float*)d_in[10];
  const float* b_ne     = (const float*)d_in[11];
  const float* W_es     = (const float*)d_in[12];
  const float* b_es     = (const float*)d_in[13];
  const float* W_ea1    = (const float*)d_in[14];
  const float* b_ea1    = (const float*)d_in[15];
  const float* W_ea2    = (const float*)d_in[16];
  const float* b_ea2    = (const float*)d_in[17];
  const float* W_as     = (const float*)d_in[18];
  const float* b_as     = (const float*)d_in[19];
  const float* res_n    = (const float*)d_in[20];
  const float* res_e    = (const float*)d_in[21];
  const float* res_a    = (const float*)d_in[22];
  const int*   nlist    = (const int*)d_in[23];

  float* out = (float*)d_out;
  float* node_out  = out;
  float* edge_out  = out + 1024*128;
  float* angle_out = out + 1024*128 + (size_t)1024*64*64;

  k0_node_pre<<<1024, 128, 0, stream>>>(node_ext, W_self, b_self, W_ne, b_ne,
                                        W_es, b_es, W_ea1, b_ea1, W_as, b_as);
  kw_prep<<<32, 256, 0, stream>>>(W_ea1, W_as);
  k2_angle<<<1024, 256, 0, stream>>>(angle, edge_ebd, a_sw, res_a,
                                     W_ea1, W_as, angle_out);
  k3_node_edge<<<1024, 256, 0, stream>>>(node_ext, edge_ebd, h2, sw, nlist,
                                         W_sym, b_sym, W_ne, W_es, W_ea2, b_ea2,
                                         res_n, res_e, node_out, edge_out);
}